// Round 6
// baseline (732.525 us; speedup 1.0000x reference)
//
#include <hip/hip_runtime.h>

#define HASH_MASK ((1u << 19) - 1u)
#define TAB_STRIDE 7131228u            // padded entries per table (poff %4 == 0)
#define SCALE 1048576.0f               // 2^20 (exact)
#define INV_SCALE 9.5367431640625e-07f // 2^-20 (exact)

typedef float    f32x2 __attribute__((ext_vector_type(2)));
typedef float    f32x4 __attribute__((ext_vector_type(4)));
typedef _Float16 f16x2 __attribute__((ext_vector_type(2)));
typedef unsigned u32x4 __attribute__((ext_vector_type(4)));

// Original (reference) level offsets and sizes.
__device__ __forceinline__ unsigned orig_off(int l) {
    if (l >= 3) return 315475u + (unsigned)(l - 3) * 524288u;
    return (l == 0) ? 0u : ((l == 1) ? 4913u : 40850u);
}
__device__ __forceinline__ unsigned hsize(int l) {
    if (l >= 3) return 524288u;
    return (l == 0) ? 4913u : ((l == 1) ? 35937u : 274625u);
}
// Padded offsets: every slice starts on a 16B boundary (entry index %4==0).
__device__ __forceinline__ unsigned poff(int l) {
    if (l >= 3) return 315484u + (unsigned)(l - 3) * 524288u;
    return (l == 0) ? 0u : ((l == 1) ? 4916u : 40856u);
}

// ---------------- pre-pass A: f32 tables -> fp16 (x 2^20), padded layout -----
__global__ __launch_bounds__(256) void convert_tables_kernel(
    const float* __restrict__ e0, const float* __restrict__ e1,
    const float* __restrict__ e2, const float* __restrict__ e3,
    f16x2* __restrict__ ws)
{
    const int l = (int)blockIdx.z;
    const unsigned hs = hsize(l);
    const unsigned i = blockIdx.x * 256u + threadIdx.x;
    if (i >= hs) return;
    const float* src = (blockIdx.y == 0) ? e0 : ((blockIdx.y == 1) ? e1
                     : ((blockIdx.y == 2) ? e2 : e3));
    const f32x2 v = __builtin_nontemporal_load(
        reinterpret_cast<const f32x2*>(src) + (orig_off(l) + i));
    f16x2 h;
    h.x = (_Float16)(v.x * SCALE);
    h.y = (_Float16)(v.y * SCALE);
    ws[blockIdx.y * TAB_STRIDE + poff(l) + i] = h;
}

// ---------------- pre-pass B: pack (x0,x1,x2,t) into one f32x4 ---------------
__global__ __launch_bounds__(256) void pack_coords_kernel(
    const float* __restrict__ x, const float* __restrict__ t,
    f32x4* __restrict__ pc, int B)
{
    const int i = blockIdx.x * 256 + threadIdx.x;
    if (i >= B) return;
    f32x4 c;
    c.x = x[i * 3 + 0];
    c.y = x[i * 3 + 1];
    c.z = x[i * 3 + 2];
    c.w = t[i];
    pc[i] = c;
}

// ------------- main pass: one (encode,level) combo per block ----------------
// blockIdx.x = combo * nchunk + chunk -> dispatch order serializes combos so
// the combo's <=2MB fp16 slice stays L2-resident on every XCD.
__global__ __launch_bounds__(256) void hg_pass_kernel(
    const f32x4* __restrict__ pc,
    const f16x2* __restrict__ ws, f16x2* __restrict__ sc,
    int B, int nchunk)
{
    const int combo = blockIdx.x / nchunk;
    const int chunk = blockIdx.x - combo * nchunk;
    const int point = chunk * 256 + threadIdx.x;
    if (point >= B) return;
    const int e = combo >> 4;     // combo = e*16 + l
    const int l = combo & 15;

    const f32x4 cc = pc[point];   // one 16B coalesced load
    // e0:(x0,x1,x2) e1:(x0,x1,t) e2:(x0,x2,t) e3:(x1,x2,t)
    const float c0 = (e == 3) ? cc.y : cc.x;
    const float c1 = (e <= 1) ? cc.y : cc.z;
    const float c2 = (e == 0) ? cc.z : cc.w;

    const f16x2* __restrict__ tab = ws + (size_t)e * TAB_STRIDE + poff(l);

    const int res = 16 << l;
    const float resf = (float)res;
    const float p0 = c0 * resf, p1 = c1 * resf, p2 = c2 * resf;
    const float fl0 = floorf(p0), fl1 = floorf(p1), fl2 = floorf(p2);
    const float f0 = p0 - fl0, f1 = p1 - fl1, f2 = p2 - fl2;
    const unsigned g0 = (unsigned)min(max((int)fl0, 0), res - 1);
    const unsigned g1 = (unsigned)min(max((int)fl1, 0), res - 1);
    const unsigned g2 = (unsigned)min(max((int)fl2, 0), res - 1);

    const bool dense = (l < 3);
    const unsigned r1 = (unsigned)(res + 1);
    const unsigned r1sq = r1 * r1;
    const unsigned d_base = g0 + g1 * r1 + g2 * r1sq;
    const unsigned h1a = g1 * 2654435761u, h1b = (g1 + 1u) * 2654435761u;
    const unsigned h2a = g2 * 805459861u,  h2b = (g2 + 1u) * 805459861u;
    const float omf0 = 1.0f - f0, omf1 = 1.0f - f1, omf2 = 1.0f - f2;

    float a0 = 0.0f, a1 = 0.0f;
#pragma unroll
    for (int pr = 0; pr < 4; ++pr) {      // (by,bz) corner pairs; bx in {0,1}
        const int by = pr & 1, bz = pr >> 1;
        const float wyz = (by ? f1 : omf1) * (bz ? f2 : omf2);
        const float w0 = omf0 * wyz, w1 = f0 * wyz;
        unsigned u0, u1;
        if (dense) {
            const unsigned b = d_base + (by ? r1 : 0u) + (bz ? r1sq : 0u);
            u0 = b; u1 = b + 1u;
        } else {
            const unsigned H = (by ? h1b : h1a) ^ (bz ? h2b : h2a);
            u0 = (g0 ^ H) & HASH_MASK;
            u1 = ((g0 + 1u) ^ H) & HASH_MASK;
        }
        unsigned w0v, w1v;
        if ((u0 ^ u1) < 4u) {
            // both corners in one aligned 16B quad: single dwordx4 gather
            const u32x4 q = *reinterpret_cast<const u32x4*>(tab + (u0 & ~3u));
            const unsigned s0 = u0 & 3u, s1 = u1 & 3u;
            w0v = (s0 & 2u) ? ((s0 & 1u) ? q.w : q.z) : ((s0 & 1u) ? q.y : q.x);
            w1v = (s1 & 2u) ? ((s1 & 1u) ? q.w : q.z) : ((s1 & 1u) ? q.y : q.x);
        } else {
            w0v = *reinterpret_cast<const unsigned*>(tab + u0);
            w1v = *reinterpret_cast<const unsigned*>(tab + u1);
        }
        const f16x2 v0 = __builtin_bit_cast(f16x2, w0v);
        const f16x2 v1 = __builtin_bit_cast(f16x2, w1v);
        a0 = fmaf(w0, (float)v0.x, fmaf(w1, (float)v1.x, a0));
        a1 = fmaf(w0, (float)v0.y, fmaf(w1, (float)v1.y, a1));
    }

    // fp16 scratch (still scaled by 2^20), combo-major, coalesced 4B/lane.
    f16x2 r;
    r.x = (_Float16)a0;
    r.y = (_Float16)a1;
    __builtin_nontemporal_store(r, &sc[(size_t)combo * (size_t)B + (size_t)point]);
}

// ------------- transpose: sc[64 combos][B] (fp16) -> out[B][128] (f32) ------
__global__ __launch_bounds__(256) void transpose_kernel(
    const f16x2* __restrict__ sc, float* __restrict__ out, int B)
{
    __shared__ f16x2 tile[64][65];   // 65 pad: conflict-free both phases
    const int pbase = blockIdx.x * 64;
    const int tid = (int)threadIdx.x;

    const int prr = tid & 63;
    const int gp_r = pbase + prr;
#pragma unroll
    for (int i = 0; i < 16; ++i) {
        const int c = i * 4 + (tid >> 6);
        if (gp_r < B)
            tile[prr][c] = __builtin_nontemporal_load(&sc[(size_t)c * (size_t)B + (size_t)gp_r]);
    }
    __syncthreads();

    const int wv = tid >> 6;         // wave id 0..3
    const int ln = tid & 63;         // lane = combo
#pragma unroll
    for (int j = 0; j < 16; ++j) {
        const int p = wv * 16 + j;
        const int gp = pbase + p;
        if (gp < B) {
            const f16x2 v = tile[p][ln];
            f32x2 o;
            o.x = (float)v.x * INV_SCALE;
            o.y = (float)v.y * INV_SCALE;
            __builtin_nontemporal_store(o, reinterpret_cast<f32x2*>(out + (size_t)gp * 128 + ln * 2));
        }
    }
}

// ---------------- fallback: f32 fused (no workspace needed) -----------------
__global__ __launch_bounds__(256) void hashgrid4d_f32_kernel(
    const float* __restrict__ x, const float* __restrict__ t,
    const float* __restrict__ e0, const float* __restrict__ e1,
    const float* __restrict__ e2, const float* __restrict__ e3,
    float* __restrict__ out, int B)
{
    const int gid   = blockIdx.x * blockDim.x + threadIdx.x;
    const int point = gid >> 6;
    if (point >= B) return;
    const int lane = threadIdx.x & 63;
    const int l = lane & 15;
    const int e = lane >> 4;

    const float x0 = x[point * 3 + 0], x1 = x[point * 3 + 1], x2 = x[point * 3 + 2];
    const float tt = t[point];
    const float c0 = (e == 3) ? x1 : x0;
    const float c1 = (e <= 1) ? x1 : x2;
    const float c2 = (e == 0) ? x2 : tt;
    const float* tab = (e == 0) ? e0 : ((e == 1) ? e1 : ((e == 2) ? e2 : e3));

    const int res = 16 << l;
    const float resf = (float)res;
    const float p0 = c0 * resf, p1 = c1 * resf, p2 = c2 * resf;
    const float fl0 = floorf(p0), fl1 = floorf(p1), fl2 = floorf(p2);
    const float f0 = p0 - fl0, f1 = p1 - fl1, f2 = p2 - fl2;
    const unsigned g0 = (unsigned)min(max((int)fl0, 0), res - 1);
    const unsigned g1 = (unsigned)min(max((int)fl1, 0), res - 1);
    const unsigned g2 = (unsigned)min(max((int)fl2, 0), res - 1);
    const bool dense = (l < 3);
    const unsigned offs = orig_off(l);
    const unsigned r1 = (unsigned)(res + 1), r1sq = r1 * r1;
    const unsigned d_base = g0 + g1 * r1 + g2 * r1sq;
    const unsigned h1a = g1 * 2654435761u, h1b = (g1 + 1u) * 2654435761u;
    const unsigned h2a = g2 * 805459861u,  h2b = (g2 + 1u) * 805459861u;
    const float omf0 = 1.0f - f0, omf1 = 1.0f - f1, omf2 = 1.0f - f2;

    float a0 = 0.0f, a1 = 0.0f;
#pragma unroll
    for (int c = 0; c < 8; ++c) {
        const int bx = c & 1, by = (c >> 1) & 1, bz = c >> 2;
        const float w = (bx ? f0 : omf0) * (by ? f1 : omf1) * (bz ? f2 : omf2);
        const unsigned di = d_base + (bx ? 1u : 0u) + (by ? r1 : 0u) + (bz ? r1sq : 0u);
        const unsigned hi = (((g0 + (unsigned)bx) ^ (by ? h1b : h1a) ^ (bz ? h2b : h2a)) & HASH_MASK);
        const unsigned idx = dense ? di : hi;
        const f32x2 v = *reinterpret_cast<const f32x2*>(tab + 2u * (offs + idx));
        a0 = fmaf(w, v.x, a0);
        a1 = fmaf(w, v.y, a1);
    }
    f32x2 r; r.x = a0; r.y = a1;
    __builtin_nontemporal_store(r, reinterpret_cast<f32x2*>(out + (size_t)point * 128 + lane * 2));
}

extern "C" void kernel_launch(void* const* d_in, const int* in_sizes, int n_in,
                              void* d_out, int out_size, void* d_ws, size_t ws_size,
                              hipStream_t stream) {
    const float* x  = (const float*)d_in[0];
    const float* t  = (const float*)d_in[1];
    const float* e0 = (const float*)d_in[2];
    const float* e1 = (const float*)d_in[3];
    const float* e2 = (const float*)d_in[4];
    const float* e3 = (const float*)d_in[5];
    float* out = (float*)d_out;
    const int B = in_sizes[0] / 3;

    const size_t tab_bytes = (size_t)TAB_STRIDE * 4u * sizeof(f16x2); // 114.1 MB
    const size_t sc_bytes  = (size_t)B * 64u * sizeof(f16x2);         // 128 MB
    const size_t pc_bytes  = (size_t)B * sizeof(f32x4);               // 8 MB

    if (ws_size >= tab_bytes + sc_bytes + pc_bytes) {
        f16x2* wtab = (f16x2*)d_ws;
        f16x2* sc   = (f16x2*)((char*)d_ws + tab_bytes);
        f32x4* pcd  = (f32x4*)((char*)d_ws + tab_bytes + sc_bytes);

        dim3 cgrid(2048, 4, 16);  // x: up to 524288 entries/level, y: table, z: level
        convert_tables_kernel<<<cgrid, 256, 0, stream>>>(e0, e1, e2, e3, wtab);
        pack_coords_kernel<<<(B + 255) / 256, 256, 0, stream>>>(x, t, pcd, B);

        int nchunk = (B + 255) / 256;
        nchunk = (nchunk + 7) & ~7;              // %8==0 -> chunk->XCD striping
        hg_pass_kernel<<<64 * nchunk, 256, 0, stream>>>(pcd, wtab, sc, B, nchunk);

        transpose_kernel<<<(B + 63) / 64, 256, 0, stream>>>(sc, out, B);
    } else {
        const long long total = (long long)B * 64;
        const int blocks = (int)((total + 255) / 256);
        hashgrid4d_f32_kernel<<<blocks, 256, 0, stream>>>(x, t, e0, e1, e2, e3, out, B);
    }
}